// Round 4
// baseline (251.662 us; speedup 1.0000x reference)
//
#include <hip/hip_runtime.h>

#define NB 8732
#define NC 21
#define BATCH 128
#define BX 35   // ceil(8732/256) blocks along boxes

__device__ inline float wred_f(float v) {
#pragma unroll
    for (int o = 32; o > 0; o >>= 1) v += __shfl_down(v, o, 64);
    return v;
}
__device__ inline int wred_i(int v) {
#pragma unroll
    for (int o = 32; o > 0; o >>= 1) v += __shfl_down(v, o, 64);
    return v;
}

// Wave-cooperative tile: wave = 64 boxes = 1344 contiguous floats.
// Coalesced dword loads (4 lines/instr, each line exactly once) -> wave-private
// LDS transpose (write stride-1, read stride-21: both 2-way alias = free) ->
// per-lane softmax. No __syncthreads in the main path; waves stay independent.
__global__ void __launch_bounds__(256)
kA(const float* __restrict__ locp, const float* __restrict__ loct,
   const float* __restrict__ conf, const int* __restrict__ lab,
   float* __restrict__ row_ce, float* __restrict__ row_pce,
   int* __restrict__ row_np, float* __restrict__ loc_acc,
   int* __restrict__ nm_acc) {
    __shared__ float xb[4][1344];
    const int r = blockIdx.y;
    const int w = threadIdx.x >> 6;
    const int ln = threadIdx.x & 63;
    const int box0 = blockIdx.x * 256 + w * 64;

    float ceS = 0.f, pceS = 0.f, llS = 0.f;
    int npS = 0;

    if (box0 < NB) {
        const int cnt = min(64, NB - box0);
        const size_t rowbase = (size_t)r * NB;
        const float* __restrict__ src = conf + (rowbase + box0) * (size_t)NC;

        // per-box side loads issued early (coalesced), in flight during transpose
        int l = 0;
        float4 lp = {0.f, 0.f, 0.f, 0.f}, lt = {0.f, 0.f, 0.f, 0.f};
        if (ln < cnt) {
            const size_t box = rowbase + box0 + ln;
            l = lab[box];
            lp = *(const float4*)(locp + box * 4);
            lt = *(const float4*)(loct + box * 4);
        }

        if (cnt == 64) {
            float v[21];
#pragma unroll
            for (int j = 0; j < 21; j++) v[j] = src[64 * j + ln];
#pragma unroll
            for (int j = 0; j < 21; j++) xb[w][64 * j + ln] = v[j];
        } else {
            const int nflat = cnt * NC;
#pragma unroll
            for (int j = 0; j < 21; j++) {
                const int idx = 64 * j + ln;
                if (idx < nflat) xb[w][idx] = src[idx];
            }
        }
        // wave-local cross-lane LDS dependency: drain DS queue, no barrier
        asm volatile("s_waitcnt lgkmcnt(0)" ::: "memory");

        if (ln < cnt) {
            float c[21];
            const float* bp = &xb[w][21 * ln];
#pragma unroll
            for (int j = 0; j < 21; j++) c[j] = bp[j];
            float m = c[0];
#pragma unroll
            for (int j = 1; j < 21; j++) m = fmaxf(m, c[j]);
            float s = 0.f;
#pragma unroll
            for (int j = 0; j < 21; j++) s += __expf(c[j] - m);
            float gold = c[0];
#pragma unroll
            for (int j = 1; j < 21; j++) gold = (j == l) ? c[j] : gold;
            const float ce = m + __logf(s) - gold;
            ceS = ce;
            if (l > 0) {
                npS = 1;
                pceS = ce;
                float d, ad;
                d = lp.x - lt.x; ad = fabsf(d); llS += (ad < 1.f) ? 0.5f * d * d : ad - 0.5f;
                d = lp.y - lt.y; ad = fabsf(d); llS += (ad < 1.f) ? 0.5f * d * d : ad - 0.5f;
                d = lp.z - lt.z; ad = fabsf(d); llS += (ad < 1.f) ? 0.5f * d * d : ad - 0.5f;
                d = lp.w - lt.w; ad = fabsf(d); llS += (ad < 1.f) ? 0.5f * d * d : ad - 0.5f;
            }
        }
    }

    __shared__ float sr[3][4];
    __shared__ int si[4];
    float v0 = wred_f(ceS), v1 = wred_f(pceS), v2 = wred_f(llS);
    int v3 = wred_i(npS);
    if (ln == 0) { sr[0][w] = v0; sr[1][w] = v1; sr[2][w] = v2; si[w] = v3; }
    __syncthreads();
    if (threadIdx.x == 0) {
        float A = 0, B = 0, C = 0; int D = 0;
#pragma unroll
        for (int k = 0; k < 4; k++) { A += sr[0][k]; B += sr[1][k]; C += sr[2][k]; D += si[k]; }
        atomicAdd(&row_ce[r], A);
        atomicAdd(&row_pce[r], B);
        atomicAdd(loc_acc, C);
        atomicAdd(&row_np[r], D);
        atomicAdd(nm_acc, D);
    }
}

__device__ inline float ce_for_box0(const float* __restrict__ cp) {
    float c[NC];
#pragma unroll
    for (int j = 0; j < NC; j++) c[j] = cp[j];
    float m = c[0];
#pragma unroll
    for (int j = 1; j < NC; j++) m = fmaxf(m, c[j]);
    float s = 0.f;
#pragma unroll
    for (int j = 0; j < NC; j++) s += __expf(c[j] - m);
    return m + __logf(s) - c[0];
}

// Per-row mining + conf accumulation; LAST block finalizes output.
// Hot path (K >= #neg, always true on this data): conf_row = row_ce, no sort.
// Cold path: exact top-K via radix select (tie values identical -> sum exact).
__global__ void __launch_bounds__(256)
kB(const float* __restrict__ conf, const int* __restrict__ lab,
   const float* __restrict__ row_ce, const float* __restrict__ row_pce,
   const int* __restrict__ row_np, float* __restrict__ conf_acc,
   float* __restrict__ loc_acc, int* __restrict__ nm_acc,
   int* __restrict__ done, float* __restrict__ out) {
    const int r = blockIdx.x;
    const int np = row_np[r];
    const int K = min(3 * np, NB - 1);
    const int nneg = NB - np;

    float rowval = 0.f;
    if (K >= nneg) {
        rowval = row_ce[r];
    } else if (K <= 0) {
        rowval = row_pce[r];
    } else {
        __shared__ unsigned key[NB];
        __shared__ unsigned hist[256];
        __shared__ unsigned sb[2];
        for (int i = threadIdx.x; i < NB; i += 256) {
            const long box = (long)r * NB + i;
            unsigned k = 0u;
            if (lab[box] == 0) {
                float ce = ce_for_box0(conf + box * (long)NC);
                k = __float_as_uint(fmaxf(ce, 0.f));
            }
            key[i] = k;
        }
        __syncthreads();
        unsigned prefix = 0;
        int Kr = K;
        for (int round = 3; round >= 0; --round) {
            const int sh = round * 8;
            const unsigned pmask = (round == 3) ? 0u : (0xFFFFFFFFu << (8 * (round + 1)));
            for (int b = threadIdx.x; b < 256; b += 256) hist[b] = 0;
            __syncthreads();
            for (int i = threadIdx.x; i < NB; i += 256) {
                const unsigned k = key[i];
                if ((k & pmask) == prefix) atomicAdd(&hist[(k >> sh) & 255u], 1u);
            }
            __syncthreads();
            if (threadIdx.x == 0) {
                unsigned cum = 0; int b = 255;
                for (; b > 0; --b) {
                    const unsigned h = hist[b];
                    if (cum + h >= (unsigned)Kr) break;
                    cum += h;
                }
                sb[0] = cum; sb[1] = (unsigned)b;
            }
            __syncthreads();
            Kr -= (int)sb[0];
            prefix |= (sb[1] << sh);
            __syncthreads();
        }
        float local = 0.f;
        for (int i = threadIdx.x; i < NB; i += 256) {
            const unsigned k = key[i];
            if (k > prefix) local += __uint_as_float(k);
        }
        __shared__ float sred[4];
        float v = wred_f(local);
        const int w = threadIdx.x >> 6, ln = threadIdx.x & 63;
        if (ln == 0) sred[w] = v;
        __syncthreads();
        rowval = row_pce[r] + sred[0] + sred[1] + sred[2] + sred[3]
               + (float)Kr * __uint_as_float(prefix);
    }

    if (threadIdx.x == 0) {
        atomicAdd(conf_acc, rowval);
        __threadfence();
        const int old = atomicAdd(done, 1);
        if (old == BATCH - 1) {
            const float cf = atomicAdd(conf_acc, 0.f);
            const float lc = atomicAdd(loc_acc, 0.f);
            const int nm = atomicAdd(nm_acc, 0);
            out[0] = (lc + cf) / fmaxf((float)nm, 1.f);
        }
    }
}

extern "C" void kernel_launch(void* const* d_in, const int* in_sizes, int n_in,
                              void* d_out, int out_size, void* d_ws, size_t ws_size,
                              hipStream_t stream) {
    const float* locp = (const float*)d_in[0];
    const float* loct = (const float*)d_in[1];
    const float* conf = (const float*)d_in[2];
    const int* lab = (const int*)d_in[3];
    float* out = (float*)d_out;

    float* loc_acc = (float*)d_ws;
    float* conf_acc = loc_acc + 1;
    int* nm_acc = (int*)d_ws + 2;
    int* done = (int*)d_ws + 3;
    float* row_ce = (float*)d_ws + 16;
    float* row_pce = row_ce + BATCH;
    int* row_np = (int*)(row_pce + BATCH);

    hipMemsetAsync(d_ws, 0, 4096, stream);

    hipLaunchKernelGGL(kA, dim3(BX, BATCH), dim3(256), 0, stream,
                       locp, loct, conf, lab, row_ce, row_pce, row_np, loc_acc, nm_acc);
    hipLaunchKernelGGL(kB, dim3(BATCH), dim3(256), 0, stream,
                       conf, lab, row_ce, row_pce, row_np, conf_acc, loc_acc, nm_acc, done, out);
}

// Round 5
// 178.447 us; speedup vs baseline: 1.4103x; 1.4103x over previous
//
#include <hip/hip_runtime.h>

#define NB 8732
#define NC 21
#define BATCH 128
#define BX 35   // ceil(8732/256)

__device__ inline float wred_f(float v) {
#pragma unroll
    for (int o = 32; o > 0; o >>= 1) v += __shfl_down(v, o, 64);
    return v;
}
__device__ inline int wred_i(int v) {
#pragma unroll
    for (int o = 32; o > 0; o >>= 1) v += __shfl_down(v, o, 64);
    return v;
}

// ws layout (dwords): [0]=done  [16..143]=kbOut[128]
// [256 + r*16 + {0,1,2,3}] = rowAcc[r] = {ce, pce, loc, np} (64B-padded line/row)
#define WS_DONE 0
#define WS_KBOUT 16
#define WS_ROWACC 256
#define WS_ZERO_BYTES 12288

// Thread = 1 box, 21 scalar conf loads (r1 body — base ~12us). Epilogue:
// per-ROW atomic lines only (35-way contention, 128 independent lines).
// NO grid-wide single-address atomics — that was the 60-120us serializer.
__global__ void __launch_bounds__(256)
kA(const float* __restrict__ locp, const float* __restrict__ loct,
   const float* __restrict__ conf, const int* __restrict__ lab,
   float* __restrict__ ws) {
    const int r = blockIdx.y;
    const int i = blockIdx.x * 256 + threadIdx.x;
    float ce = 0.f, pce = 0.f, ll = 0.f;
    int pc = 0;
    if (i < NB) {
        const size_t box = (size_t)r * NB + i;
        const int l = lab[box];
        const float* cp = conf + box * (size_t)NC;
        float c[NC];
#pragma unroll
        for (int j = 0; j < NC; j++) c[j] = cp[j];
        float m = c[0];
#pragma unroll
        for (int j = 1; j < NC; j++) m = fmaxf(m, c[j]);
        float s = 0.f;
#pragma unroll
        for (int j = 0; j < NC; j++) s += __expf(c[j] - m);
        float gold = c[0];
#pragma unroll
        for (int j = 1; j < NC; j++) gold = (j == l) ? c[j] : gold;
        ce = m + __logf(s) - gold;
        if (l > 0) {
            pc = 1; pce = ce;
            const float4 lp = *(const float4*)(locp + box * 4);
            const float4 lt = *(const float4*)(loct + box * 4);
            float d, ad;
            d = lp.x - lt.x; ad = fabsf(d); ll += (ad < 1.f) ? 0.5f * d * d : ad - 0.5f;
            d = lp.y - lt.y; ad = fabsf(d); ll += (ad < 1.f) ? 0.5f * d * d : ad - 0.5f;
            d = lp.z - lt.z; ad = fabsf(d); ll += (ad < 1.f) ? 0.5f * d * d : ad - 0.5f;
            d = lp.w - lt.w; ad = fabsf(d); ll += (ad < 1.f) ? 0.5f * d * d : ad - 0.5f;
        }
    }

    __shared__ float sr[3][4];
    __shared__ int si[4];
    float v0 = wred_f(ce), v1 = wred_f(pce), v2 = wred_f(ll);
    int v3 = wred_i(pc);
    const int w = threadIdx.x >> 6, ln = threadIdx.x & 63;
    if (ln == 0) { sr[0][w] = v0; sr[1][w] = v1; sr[2][w] = v2; si[w] = v3; }
    __syncthreads();
    if (threadIdx.x == 0) {
        float A = 0, B = 0, C = 0; int D = 0;
#pragma unroll
        for (int k = 0; k < 4; k++) { A += sr[0][k]; B += sr[1][k]; C += sr[2][k]; D += si[k]; }
        float* acc = ws + WS_ROWACC + r * 16;
        atomicAdd(&acc[0], A);
        atomicAdd(&acc[1], B);
        atomicAdd(&acc[2], C);
        atomicAdd((int*)&acc[3], D);
    }
}

__device__ inline float ce_for_box0(const float* __restrict__ cp) {
    float c[NC];
#pragma unroll
    for (int j = 0; j < NC; j++) c[j] = cp[j];
    float m = c[0];
#pragma unroll
    for (int j = 1; j < NC; j++) m = fmaxf(m, c[j]);
    float s = 0.f;
#pragma unroll
    for (int j = 0; j < NC; j++) s += __expf(c[j] - m);
    return m + __logf(s) - c[0];
}

// Per-row mining; spread per-row results (plain stores), 128-way done counter;
// LAST block parallel-reduces the 128 rows and writes the scalar.
// Hot path (K >= #neg, always true on this data): conf_row = row_ce, no sort.
// Cold path: exact top-K radix select (tie values identical -> sum exact).
__global__ void __launch_bounds__(256)
kB(const float* __restrict__ conf, const int* __restrict__ lab,
   float* __restrict__ ws, float* __restrict__ out) {
    const int r = blockIdx.x;
    const float* acc = ws + WS_ROWACC + r * 16;
    const int np = __float_as_int(__int_as_float(((const int*)acc)[3]));
    const int K = min(3 * np, NB - 1);
    const int nneg = NB - np;
    const float row_ce = acc[0];
    const float row_pce = acc[1];

    float rowval = 0.f;
    if (K >= nneg) {
        rowval = row_ce;
    } else if (K <= 0) {
        rowval = row_pce;
    } else {
        __shared__ unsigned key[NB];
        __shared__ unsigned hist[256];
        __shared__ unsigned sb[2];
        for (int i = threadIdx.x; i < NB; i += 256) {
            const size_t box = (size_t)r * NB + i;
            unsigned k = 0u;
            if (lab[box] == 0) {
                float ce = ce_for_box0(conf + box * (size_t)NC);
                k = __float_as_uint(fmaxf(ce, 0.f));
            }
            key[i] = k;
        }
        __syncthreads();
        unsigned prefix = 0;
        int Kr = K;
        for (int round = 3; round >= 0; --round) {
            const int sh = round * 8;
            const unsigned pmask = (round == 3) ? 0u : (0xFFFFFFFFu << (8 * (round + 1)));
            for (int b = threadIdx.x; b < 256; b += 256) hist[b] = 0;
            __syncthreads();
            for (int i = threadIdx.x; i < NB; i += 256) {
                const unsigned k = key[i];
                if ((k & pmask) == prefix) atomicAdd(&hist[(k >> sh) & 255u], 1u);
            }
            __syncthreads();
            if (threadIdx.x == 0) {
                unsigned cum = 0; int b = 255;
                for (; b > 0; --b) {
                    const unsigned h = hist[b];
                    if (cum + h >= (unsigned)Kr) break;
                    cum += h;
                }
                sb[0] = cum; sb[1] = (unsigned)b;
            }
            __syncthreads();
            Kr -= (int)sb[0];
            prefix |= (sb[1] << sh);
            __syncthreads();
        }
        float local = 0.f;
        for (int i = threadIdx.x; i < NB; i += 256) {
            const unsigned k = key[i];
            if (k > prefix) local += __uint_as_float(k);
        }
        __shared__ float sred[4];
        float v = wred_f(local);
        const int ww = threadIdx.x >> 6, lnn = threadIdx.x & 63;
        if (lnn == 0) sred[ww] = v;
        __syncthreads();
        rowval = row_pce + sred[0] + sred[1] + sred[2] + sred[3]
               + (float)Kr * __uint_as_float(prefix);
    }

    // ---- spread store + done counter; last block parallel-finalizes ----
    __shared__ int islast;
    if (threadIdx.x == 0) {
        ws[WS_KBOUT + r] = rowval;
        __threadfence();
        const int old = atomicAdd((int*)ws + WS_DONE, 1);
        islast = (old == BATCH - 1) ? 1 : 0;
    }
    __syncthreads();
    if (islast) {
        __threadfence();
        float cf = 0.f, lc = 0.f;
        int nm = 0;
        if (threadIdx.x < BATCH) {
            const int t = threadIdx.x;
            cf = ws[WS_KBOUT + t];
            const float* a = ws + WS_ROWACC + t * 16;
            lc = a[2];
            nm = ((const int*)a)[3];
        }
        __shared__ float sf[4], sl[4];
        __shared__ int sn[4];
        float vc = wred_f(cf), vl = wred_f(lc);
        int vn = wred_i(nm);
        const int w = threadIdx.x >> 6, ln = threadIdx.x & 63;
        if (ln == 0) { sf[w] = vc; sl[w] = vl; sn[w] = vn; }
        __syncthreads();
        if (threadIdx.x == 0) {
            float CF = sf[0] + sf[1] + sf[2] + sf[3];
            float LC = sl[0] + sl[1] + sl[2] + sl[3];
            int NM = sn[0] + sn[1] + sn[2] + sn[3];
            out[0] = (LC + CF) / fmaxf((float)NM, 1.f);
        }
    }
}

extern "C" void kernel_launch(void* const* d_in, const int* in_sizes, int n_in,
                              void* d_out, int out_size, void* d_ws, size_t ws_size,
                              hipStream_t stream) {
    const float* locp = (const float*)d_in[0];
    const float* loct = (const float*)d_in[1];
    const float* conf = (const float*)d_in[2];
    const int* lab = (const int*)d_in[3];
    float* out = (float*)d_out;
    float* ws = (float*)d_ws;

    hipMemsetAsync(d_ws, 0, WS_ZERO_BYTES, stream);

    hipLaunchKernelGGL(kA, dim3(BX, BATCH), dim3(256), 0, stream,
                       locp, loct, conf, lab, ws);
    hipLaunchKernelGGL(kB, dim3(BATCH), dim3(256), 0, stream,
                       conf, lab, ws, out);
}

// Round 6
// 176.222 us; speedup vs baseline: 1.4281x; 1.0126x over previous
//
#include <hip/hip_runtime.h>

#define NB 8732
#define NC 21
#define BATCH 128
#define BX 35   // ceil(8732/256)

// ws layout (dwords), ALL slots written before read -> no zero-init, no memset:
//   [ (r*35+bx)*4 + {0,1,2,3} ] = block partials {ce, pce, loc, np(float)}
//   [ WS_ROW + r*4 + {0,1,2} ]  = per-row {conf_rowval, loc_row, np_row}
#define WS_ROW (BATCH * BX * 4)

__device__ inline float wred_f(float v) {
#pragma unroll
    for (int o = 32; o > 0; o >>= 1) v += __shfl_down(v, o, 64);
    return v;
}

// Wave-cooperative tile: wave = 64 boxes = 1344 contiguous floats.
// 21 coalesced dword loads/lane (each cache line touched exactly once) ->
// wave-private LDS transpose (write stride-1, read stride-21: 2-way alias,
// free) -> per-lane softmax. No __syncthreads in main path, NO atomics:
// block plain-stores 4 partials to a private slot.
__global__ void __launch_bounds__(256)
kA(const float* __restrict__ locp, const float* __restrict__ loct,
   const float* __restrict__ conf, const int* __restrict__ lab,
   float* __restrict__ ws) {
    __shared__ float xb[4][1344];
    const int r = blockIdx.y;
    const int w = threadIdx.x >> 6;
    const int ln = threadIdx.x & 63;
    const int box0 = blockIdx.x * 256 + w * 64;

    float ceS = 0.f, pceS = 0.f, llS = 0.f, npS = 0.f;

    if (box0 < NB) {
        const int cnt = min(64, NB - box0);
        const size_t rowbase = (size_t)r * NB;
        const float* __restrict__ src = conf + (rowbase + box0) * (size_t)NC;

        // side loads issued early, in flight during the transpose
        int l = 0;
        float4 lp = {0.f, 0.f, 0.f, 0.f}, lt = {0.f, 0.f, 0.f, 0.f};
        if (ln < cnt) {
            const size_t box = rowbase + box0 + ln;
            l = lab[box];
            lp = *(const float4*)(locp + box * 4);
            lt = *(const float4*)(loct + box * 4);
        }

        if (cnt == 64) {
            float v[21];
#pragma unroll
            for (int j = 0; j < 21; j++) v[j] = src[64 * j + ln];
#pragma unroll
            for (int j = 0; j < 21; j++) xb[w][64 * j + ln] = v[j];
        } else {
            const int nflat = cnt * NC;
#pragma unroll
            for (int j = 0; j < 21; j++) {
                const int idx = 64 * j + ln;
                if (idx < nflat) xb[w][idx] = src[idx];
            }
        }
        // wave-local cross-lane LDS dependency: drain DS queue, no barrier
        asm volatile("s_waitcnt lgkmcnt(0)" ::: "memory");

        if (ln < cnt) {
            float c[21];
            const float* bp = &xb[w][21 * ln];
#pragma unroll
            for (int j = 0; j < 21; j++) c[j] = bp[j];
            float m = c[0];
#pragma unroll
            for (int j = 1; j < 21; j++) m = fmaxf(m, c[j]);
            float s = 0.f;
#pragma unroll
            for (int j = 0; j < 21; j++) s += __expf(c[j] - m);
            float gold = c[0];
#pragma unroll
            for (int j = 1; j < 21; j++) gold = (j == l) ? c[j] : gold;
            const float ce = m + __logf(s) - gold;
            ceS = ce;
            if (l > 0) {
                npS = 1.f;
                pceS = ce;
                float d, ad;
                d = lp.x - lt.x; ad = fabsf(d); llS += (ad < 1.f) ? 0.5f * d * d : ad - 0.5f;
                d = lp.y - lt.y; ad = fabsf(d); llS += (ad < 1.f) ? 0.5f * d * d : ad - 0.5f;
                d = lp.z - lt.z; ad = fabsf(d); llS += (ad < 1.f) ? 0.5f * d * d : ad - 0.5f;
                d = lp.w - lt.w; ad = fabsf(d); llS += (ad < 1.f) ? 0.5f * d * d : ad - 0.5f;
            }
        }
    }

    __shared__ float sr[4][4];
    float v0 = wred_f(ceS), v1 = wred_f(pceS), v2 = wred_f(llS), v3 = wred_f(npS);
    if (ln == 0) { sr[0][w] = v0; sr[1][w] = v1; sr[2][w] = v2; sr[3][w] = v3; }
    __syncthreads();
    if (threadIdx.x == 0) {
        float A = 0, B = 0, C = 0, D = 0;
#pragma unroll
        for (int k = 0; k < 4; k++) { A += sr[0][k]; B += sr[1][k]; C += sr[2][k]; D += sr[3][k]; }
        float* slot = ws + ((size_t)r * BX + blockIdx.x) * 4;
        slot[0] = A; slot[1] = B; slot[2] = C; slot[3] = D;   // plain stores, zero contention
    }
}

__device__ inline float ce_for_box0(const float* __restrict__ cp) {
    float c[NC];
#pragma unroll
    for (int j = 0; j < NC; j++) c[j] = cp[j];
    float m = c[0];
#pragma unroll
    for (int j = 1; j < NC; j++) m = fmaxf(m, c[j]);
    float s = 0.f;
#pragma unroll
    for (int j = 0; j < NC; j++) s += __expf(c[j] - m);
    return m + __logf(s) - c[0];
}

// Block r: reduce 35 partial slots -> row sums; mining decision.
// Hot path (K >= #neg, always true on this data): conf_row = row_ce, no sort.
// Cold path: exact top-K radix select (tie values identical -> sum exact).
__global__ void __launch_bounds__(256)
kB(const float* __restrict__ conf, const int* __restrict__ lab,
   float* __restrict__ ws) {
    const int r = blockIdx.x;
    __shared__ float srow[4];
    if (threadIdx.x < 64) {                      // wave 0 reduces the 35 slots
        float a = 0, b = 0, c = 0, d = 0;
        if (threadIdx.x < BX) {
            const float4 p = *(const float4*)(ws + ((size_t)r * BX + threadIdx.x) * 4);
            a = p.x; b = p.y; c = p.z; d = p.w;
        }
        a = wred_f(a); b = wred_f(b); c = wred_f(c); d = wred_f(d);
        if (threadIdx.x == 0) { srow[0] = a; srow[1] = b; srow[2] = c; srow[3] = d; }
    }
    __syncthreads();
    const float row_ce = srow[0], row_pce = srow[1], row_ll = srow[2];
    const int np = (int)srow[3];
    const int K = min(3 * np, NB - 1);
    const int nneg = NB - np;

    float rowval;
    if (K >= nneg) {
        rowval = row_ce;
    } else if (K <= 0) {
        rowval = row_pce;
    } else {
        __shared__ unsigned key[NB];
        __shared__ unsigned hist[256];
        __shared__ unsigned sb[2];
        for (int i = threadIdx.x; i < NB; i += 256) {
            const size_t box = (size_t)r * NB + i;
            unsigned k = 0u;
            if (lab[box] == 0) {
                float ce = ce_for_box0(conf + box * (size_t)NC);
                k = __float_as_uint(fmaxf(ce, 0.f));
            }
            key[i] = k;
        }
        __syncthreads();
        unsigned prefix = 0;
        int Kr = K;
        for (int round = 3; round >= 0; --round) {
            const int sh = round * 8;
            const unsigned pmask = (round == 3) ? 0u : (0xFFFFFFFFu << (8 * (round + 1)));
            for (int b = threadIdx.x; b < 256; b += 256) hist[b] = 0;
            __syncthreads();
            for (int i = threadIdx.x; i < NB; i += 256) {
                const unsigned k = key[i];
                if ((k & pmask) == prefix) atomicAdd(&hist[(k >> sh) & 255u], 1u);
            }
            __syncthreads();
            if (threadIdx.x == 0) {
                unsigned cum = 0; int b = 255;
                for (; b > 0; --b) {
                    const unsigned h = hist[b];
                    if (cum + h >= (unsigned)Kr) break;
                    cum += h;
                }
                sb[0] = cum; sb[1] = (unsigned)b;
            }
            __syncthreads();
            Kr -= (int)sb[0];
            prefix |= (sb[1] << sh);
            __syncthreads();
        }
        float local = 0.f;
        for (int i = threadIdx.x; i < NB; i += 256) {
            const unsigned k = key[i];
            if (k > prefix) local += __uint_as_float(k);
        }
        __shared__ float sred[4];
        float v = wred_f(local);
        const int ww = threadIdx.x >> 6, lnn = threadIdx.x & 63;
        if (lnn == 0) sred[ww] = v;
        __syncthreads();
        rowval = row_pce + sred[0] + sred[1] + sred[2] + sred[3]
               + (float)Kr * __uint_as_float(prefix);
    }

    if (threadIdx.x == 0) {
        float* o = ws + WS_ROW + r * 4;
        o[0] = rowval; o[1] = row_ll; o[2] = srow[3];
    }
}

// Single block: reduce the 128 per-row results -> final scalar.
__global__ void __launch_bounds__(256)
kC(const float* __restrict__ ws, float* __restrict__ out) {
    float cf = 0.f, lc = 0.f, nm = 0.f;
    if (threadIdx.x < BATCH) {
        const float* o = ws + WS_ROW + threadIdx.x * 4;
        cf = o[0]; lc = o[1]; nm = o[2];
    }
    __shared__ float sf[4], sl[4], sn[4];
    float vc = wred_f(cf), vl = wred_f(lc), vn = wred_f(nm);
    const int w = threadIdx.x >> 6, ln = threadIdx.x & 63;
    if (ln == 0) { sf[w] = vc; sl[w] = vl; sn[w] = vn; }
    __syncthreads();
    if (threadIdx.x == 0) {
        const float CF = sf[0] + sf[1] + sf[2] + sf[3];
        const float LC = sl[0] + sl[1] + sl[2] + sl[3];
        const float NM = sn[0] + sn[1] + sn[2] + sn[3];
        out[0] = (LC + CF) / fmaxf(NM, 1.f);
    }
}

extern "C" void kernel_launch(void* const* d_in, const int* in_sizes, int n_in,
                              void* d_out, int out_size, void* d_ws, size_t ws_size,
                              hipStream_t stream) {
    const float* locp = (const float*)d_in[0];
    const float* loct = (const float*)d_in[1];
    const float* conf = (const float*)d_in[2];
    const int* lab = (const int*)d_in[3];
    float* out = (float*)d_out;
    float* ws = (float*)d_ws;

    hipLaunchKernelGGL(kA, dim3(BX, BATCH), dim3(256), 0, stream,
                       locp, loct, conf, lab, ws);
    hipLaunchKernelGGL(kB, dim3(BATCH), dim3(256), 0, stream, conf, lab, ws);
    hipLaunchKernelGGL(kC, dim3(1), dim3(256), 0, stream, ws, out);
}